// Round 11
// baseline (194.106 us; speedup 1.0000x reference)
//
#include <hip/hip_runtime.h>

// Problem constants (fixed by setup_inputs in the reference)
#define S_SPK 2
#define B_BATCH 4
#define M_MIC 4
#define W_TAP 3
#define F_FREQ 257
#define T_TIME 512
#define C_CH 4
#define FT (F_FREQ * T_TIME)      // 131584

#define NBLK (S_SPK * B_BATCH * F_FREQ)   // 2056 blocks: blk = sb*257 + f
#define NSLOT NBLK

// clang ext_vector types: __builtin_nontemporal_load requires scalar /
// ext_vector pointee (HIP_vector_type float4 is rejected).
typedef float float4e __attribute__((ext_vector_type(4)));           // 16B aligned
typedef float float2u __attribute__((ext_vector_type(2), aligned(4)));

// ws layout: float partial[NSLOT][2]
//
// Round-10 result (190.6us, best): nt loads -> +5.5us. Remaining redundancy:
// 3 tap-waves re-read the same mix row; with nt (no L1/L2 allocate) that is
// 3x HBM traffic (demand ~219 MB). This round stages each mic row to LDS
// ONCE (waves 0..7, nt) -> demand 152 MB; +1-shifted guard-padded layout
// (mixlds[..][0]=[513]=0) kills the unfold edge branches.

__global__ __launch_bounds__(768) void pit_main_kernel(
    const float* __restrict__ masks,   // [S,B,M,W,F,T,2]
    const float* __restrict__ mixr,    // [S,B,M,F,T]
    const float* __restrict__ mixi,    // [S,B,M,F,T]
    const float* __restrict__ tgtr,    // [S,B,C,F,T] (use c=0)
    const float* __restrict__ tgti,    // [S,B,C,F,T]
    float* __restrict__ ws)
{
    const int blk  = blockIdx.x;
    const int sb   = blk / F_FREQ;          // so*B + b  (0..7)
    const int f    = blk - sb * F_FREQ;     // 0..256
    const int b    = sb & 3;
    const int wv   = threadIdx.x >> 6;      // 0..11 = mw stream id
    const int lane = threadIdx.x & 63;
    const int m    = wv / 3;                // mic
    const int w    = wv - m * 3;            // tap

    // [mw][t*2+comp]: per-stream partial (or,oi) for all 512 t. 48 KB.
    __shared__ float part[12][1024];
    // mixlds[m][comp][1+t] = mix[t]; [0] and [513] are zero guards. 16.4 KB.
    __shared__ float mixlds[M_MIC][2][514];

    // ---- issue mask loads: wave wv reads its (m,w) row, 4x coalesced nt ----
    const float* mrow = masks + ((long)(sb * 12 + wv) * F_FREQ + f) * (T_TIME * 2);
    float4e q[4];
    #pragma unroll
    for (int c = 0; c < 4; ++c)             // 4 x 1KB coalesced (lane-stride 16B)
        q[c] = __builtin_nontemporal_load((const float4e*)(mrow + c * 256 + (lane << 2)));

    // ---- stage mix rows to LDS: waves 0..7 = (mic, comp), single nt read ----
    if (wv < 8) {
        const int sm = wv >> 1, comp = wv & 1;
        const float* src = (comp ? mixi : mixr)
                         + (long)(sb * M_MIC + sm) * FT + (long)f * T_TIME;
        #pragma unroll
        for (int c2 = 0; c2 < 2; ++c2) {
            const float4e v = __builtin_nontemporal_load(
                (const float4e*)(src + c2 * 256 + (lane << 2)));
            const int base = 1 + c2 * 256 + (lane << 2);
            mixlds[sm][comp][base + 0] = v.x;
            mixlds[sm][comp][base + 1] = v.y;
            mixlds[sm][comp][base + 2] = v.z;
            mixlds[sm][comp][base + 3] = v.w;
        }
    } else if (lane == 0) {                 // waves 8..11: zero the guards
        const int gm = wv - 8;
        mixlds[gm][0][0] = 0.0f; mixlds[gm][0][513] = 0.0f;
        mixlds[gm][1][0] = 0.0f; mixlds[gm][1][513] = 0.0f;
    }

    // ---- hoisted phase-2 target loads (latency hides under phase 1) ----
    float t0r = 0.f, t0i = 0.f, t1r = 0.f, t1i = 0.f;
    if (threadIdx.x < 512) {
        const long to = (long)f * T_TIME + threadIdx.x;
        t0r = __builtin_nontemporal_load(tgtr + (long)(0 * B_BATCH + b) * C_CH * FT + to);
        t0i = __builtin_nontemporal_load(tgti + (long)(0 * B_BATCH + b) * C_CH * FT + to);
        t1r = __builtin_nontemporal_load(tgtr + (long)(1 * B_BATCH + b) * C_CH * FT + to);
        t1i = __builtin_nontemporal_load(tgti + (long)(1 * B_BATCH + b) * C_CH * FT + to);
    }

    __syncthreads();                        // mix staged; masks already in regs

    // ---- complex partial products -> LDS --------------------------------
    // out(t) needs win[w][t] = mix[t+w-1] = mixlds[t+w] (guarded zero-pad).
    #pragma unroll
    for (int c = 0; c < 4; ++c) {
        const int idx = c * 128 + (lane << 1) + w;   // t0 + w, in [0..512]
        const float xr0 = mixlds[m][0][idx];
        const float xr1 = mixlds[m][0][idx + 1];
        const float xi0 = mixlds[m][1][idx];
        const float xi1 = mixlds[m][1][idx + 1];
        float4e o;
        o.x = xr0 * q[c].x - xi0 * q[c].y;   // or(t0)
        o.y = xr0 * q[c].y + xi0 * q[c].x;   // oi(t0)
        o.z = xr1 * q[c].z - xi1 * q[c].w;   // or(t0+1)
        o.w = xr1 * q[c].w + xi1 * q[c].z;   // oi(t0+1)
        *(float4e*)&part[wv][c * 256 + (lane << 2)] = o;
    }
    __syncthreads();

    // ---- phase 2: threads 0..511 each own one t -------------------------
    float L0 = 0.0f, L1 = 0.0f;
    if (threadIdx.x < 512) {
        const int t = threadIdx.x;
        float orr = 0.0f, oii = 0.0f;
        #pragma unroll
        for (int mw = 0; mw < 12; ++mw) {
            const float2u p = *(const float2u*)&part[mw][t * 2];
            orr += p.x;
            oii += p.y;
        }
        const float ao = sqrtf(orr * orr + oii * oii);
        const float a0 = sqrtf(t0r * t0r + t0i * t0i);
        const float a1 = sqrtf(t1r * t1r + t1i * t1i);
        L0 = fabsf(t0r - orr) + fabsf(t0i - oii) + fabsf(a0 - ao);
        L1 = fabsf(t1r - orr) + fabsf(t1i - oii) + fabsf(a1 - ao);
    }

    // ---- block reduction (12 waves; waves 8..11 contribute 0) -----------
    #pragma unroll
    for (int off = 32; off > 0; off >>= 1) {
        L0 += __shfl_down(L0, off, 64);
        L1 += __shfl_down(L1, off, 64);
    }
    __shared__ float s0[12], s1[12];
    if (lane == 0) { s0[wv] = L0; s1[wv] = L1; }
    __syncthreads();
    if (threadIdx.x == 0) {
        float a = 0.0f, c = 0.0f;
        #pragma unroll
        for (int i = 0; i < 12; ++i) { a += s0[i]; c += s1[i]; }
        ws[blk * 2 + 0] = a;
        ws[blk * 2 + 1] = c;
    }
}

// One block, 256 threads: reduce NSLOT x 2 partials into L[so][st][b],
// then permutation-min. Kernel-boundary dependency makes partials coherent.
__global__ __launch_bounds__(256) void pit_final_kernel(
    const float* __restrict__ ws, float* __restrict__ out, int num_utts)
{
    float acc[16];                       // [so][st][b] = (so*2+st)*4+b
    #pragma unroll
    for (int i = 0; i < 16; ++i) acc[i] = 0.0f;

    for (int slot = threadIdx.x; slot < NSLOT; slot += 256) {
        const int sb = slot / F_FREQ;    // producer's sb
        const int so = sb >> 2;
        const int b  = sb & 3;
        acc[((so * 2 + 0) << 2) + b] += ws[slot * 2 + 0];
        acc[((so * 2 + 1) << 2) + b] += ws[slot * 2 + 1];
    }

    __shared__ float red[16][4];
    const int wave = threadIdx.x >> 6;
    const int lane = threadIdx.x & 63;
    #pragma unroll
    for (int i = 0; i < 16; ++i) {
        float v = acc[i];
        #pragma unroll
        for (int off = 32; off > 0; off >>= 1) v += __shfl_down(v, off, 64);
        if (lane == 0) red[i][wave] = v;
    }
    __syncthreads();

    if (threadIdx.x == 0) {
        float L[16];
        #pragma unroll
        for (int i = 0; i < 16; ++i) L[i] = red[i][0] + red[i][1] + red[i][2] + red[i][3];
        float accu = 0.0f;
        for (int b = 0; b < B_BATCH; ++b) {
            // perm (0,1): L[0][0]+L[1][1];  perm (1,0): L[0][1]+L[1][0]
            const float pid = L[(0 * 2 + 0) * 4 + b] + L[(1 * 2 + 1) * 4 + b];
            const float psw = L[(0 * 2 + 1) * 4 + b] + L[(1 * 2 + 0) * 4 + b];
            const float sc0 = 3.0f * pid / (float)S_SPK;
            const float sc1 = 3.0f * psw / (float)S_SPK;
            accu += fminf(sc0, sc1);
        }
        out[0] = accu / (float)num_utts;
    }
}

extern "C" void kernel_launch(void* const* d_in, const int* in_sizes, int n_in,
                              void* d_out, int out_size, void* d_ws, size_t ws_size,
                              hipStream_t stream) {
    const float* masks = (const float*)d_in[0];
    const float* mixr  = (const float*)d_in[1];
    const float* mixi  = (const float*)d_in[2];
    const float* tgtr  = (const float*)d_in[3];
    const float* tgti  = (const float*)d_in[4];
    // input_sizes values are never used by the reference; only its length is.
    const int num_utts = in_sizes[5];

    float* ws  = (float*)d_ws;
    float* out = (float*)d_out;

    pit_main_kernel<<<NBLK, 768, 0, stream>>>(masks, mixr, mixi, tgtr, tgti, ws);

    pit_final_kernel<<<1, 256, 0, stream>>>(ws, out, num_utts);
}

// Round 12
// 190.491 us; speedup vs baseline: 1.0190x; 1.0190x over previous
//
#include <hip/hip_runtime.h>

// Problem constants (fixed by setup_inputs in the reference)
#define S_SPK 2
#define B_BATCH 4
#define M_MIC 4
#define W_TAP 3
#define F_FREQ 257
#define T_TIME 512
#define C_CH 4
#define FT (F_FREQ * T_TIME)      // 131584

#define NBLK (S_SPK * B_BATCH * F_FREQ)   // 2056 blocks: blk = sb*257 + f
#define NSLOT NBLK

// clang ext_vector types: __builtin_nontemporal_load requires scalar /
// ext_vector pointee (HIP_vector_type float4 is rejected).
typedef float float4e __attribute__((ext_vector_type(4)));           // 16B aligned
typedef float float2u __attribute__((ext_vector_type(2), aligned(4)));

// ws layout: float partial[NSLOT][2]
//
// FINAL (revert to round-10 best, 190.6us): nt loads + dense-frontier
// stream-per-wave structure. Round-11's mix LDS dedup regressed (194.1):
// the extra barrier + LDS window reads cost more than the HBM bytes saved -
// the kernel is latency-bound at ~2.5 TB/s demand-read, not bytes-bound.
//   block = (sb,f); wave mw in [0,12) reads its (m,w) mask T-row (4 KB) in
//   4 contiguous coalesced nt float4 loads + its mix row (nt); partials via
//   LDS; phase-2 target loads hoisted above the barrier.

__global__ __launch_bounds__(768) void pit_main_kernel(
    const float* __restrict__ masks,   // [S,B,M,W,F,T,2]
    const float* __restrict__ mixr,    // [S,B,M,F,T]
    const float* __restrict__ mixi,    // [S,B,M,F,T]
    const float* __restrict__ tgtr,    // [S,B,C,F,T] (use c=0)
    const float* __restrict__ tgti,    // [S,B,C,F,T]
    float* __restrict__ ws)
{
    const int blk  = blockIdx.x;
    const int sb   = blk / F_FREQ;          // so*B + b  (0..7)
    const int f    = blk - sb * F_FREQ;     // 0..256
    const int b    = sb & 3;
    const int wv   = threadIdx.x >> 6;      // 0..11 = mw stream id
    const int lane = threadIdx.x & 63;
    const int m    = wv / 3;                // mic
    const int w    = wv - m * 3;            // tap

    // [mw][t*2+comp]: per-stream partial (or,oi) for all 512 t. 48 KB.
    __shared__ float part[12][1024];

    // ---- phase 1: each wave = one (m,w) stream --------------------------
    // masks row for (sb, m, w, f): 1024 floats, 4KB-aligned, contiguous.
    const float* mrow = masks + ((long)(sb * 12 + wv) * F_FREQ + f) * (T_TIME * 2);
    float4e q[4];
    #pragma unroll
    for (int c = 0; c < 4; ++c)             // 4 x 1KB coalesced (lane-stride 16B)
        q[c] = __builtin_nontemporal_load((const float4e*)(mrow + c * 256 + (lane << 2)));

    // mix row m for this f: window value pair (mix[t0+w-1], mix[t0+w]).
    const float* mxr = mixr + ((long)(sb * M_MIC + m) * FT) + (long)f * T_TIME;
    const float* mxi = mixi + ((long)(sb * M_MIC + m) * FT) + (long)f * T_TIME;
    float2u xr[4], xi[4];
    #pragma unroll
    for (int c = 0; c < 4; ++c) {
        const int t0 = c * 128 + (lane << 1);
        int a = t0 + w - 1;                 // -1 .. 511
        a = a < 0 ? 0 : (a > 510 ? 510 : a);
        xr[c] = __builtin_nontemporal_load((const float2u*)(mxr + a));
        xi[c] = __builtin_nontemporal_load((const float2u*)(mxi + a));
    }

    // ---- hoisted phase-2 target loads (independent of LDS; latency hides
    // under the products + barrier) ---------------------------------------
    float t0r = 0.f, t0i = 0.f, t1r = 0.f, t1i = 0.f;
    if (threadIdx.x < 512) {
        const long to = (long)f * T_TIME + threadIdx.x;
        t0r = __builtin_nontemporal_load(tgtr + (long)(0 * B_BATCH + b) * C_CH * FT + to);
        t0i = __builtin_nontemporal_load(tgti + (long)(0 * B_BATCH + b) * C_CH * FT + to);
        t1r = __builtin_nontemporal_load(tgtr + (long)(1 * B_BATCH + b) * C_CH * FT + to);
        t1i = __builtin_nontemporal_load(tgti + (long)(1 * B_BATCH + b) * C_CH * FT + to);
    }

    // edge fixups (zero padding of the unfold)
    if (w == 0 && lane == 0) {   // c=0: t0=0, a=-1: loaded (m0,m1) want (0,m0)
        xr[0].y = xr[0].x; xr[0].x = 0.0f;
        xi[0].y = xi[0].x; xi[0].x = 0.0f;
    }
    if (w == 2 && lane == 63) {  // c=3: t0=510, a=511->510: loaded (m510,m511) want (m511,0)
        xr[3].x = xr[3].y; xr[3].y = 0.0f;
        xi[3].x = xi[3].y; xi[3].y = 0.0f;
    }

    // complex partial products -> LDS
    #pragma unroll
    for (int c = 0; c < 4; ++c) {
        float4e o;
        o.x = xr[c].x * q[c].x - xi[c].x * q[c].y;   // or(t0)
        o.y = xr[c].x * q[c].y + xi[c].x * q[c].x;   // oi(t0)
        o.z = xr[c].y * q[c].z - xi[c].y * q[c].w;   // or(t0+1)
        o.w = xr[c].y * q[c].w + xi[c].y * q[c].z;   // oi(t0+1)
        *(float4e*)&part[wv][c * 256 + (lane << 2)] = o;
    }
    __syncthreads();

    // ---- phase 2: threads 0..511 each own one t -------------------------
    float L0 = 0.0f, L1 = 0.0f;
    if (threadIdx.x < 512) {
        const int t = threadIdx.x;
        float orr = 0.0f, oii = 0.0f;
        #pragma unroll
        for (int mw = 0; mw < 12; ++mw) {
            const float2u p = *(const float2u*)&part[mw][t * 2];
            orr += p.x;
            oii += p.y;
        }
        const float ao = sqrtf(orr * orr + oii * oii);
        const float a0 = sqrtf(t0r * t0r + t0i * t0i);
        const float a1 = sqrtf(t1r * t1r + t1i * t1i);
        L0 = fabsf(t0r - orr) + fabsf(t0i - oii) + fabsf(a0 - ao);
        L1 = fabsf(t1r - orr) + fabsf(t1i - oii) + fabsf(a1 - ao);
    }

    // ---- block reduction (12 waves; waves 8..11 contribute 0) -----------
    #pragma unroll
    for (int off = 32; off > 0; off >>= 1) {
        L0 += __shfl_down(L0, off, 64);
        L1 += __shfl_down(L1, off, 64);
    }
    __shared__ float s0[12], s1[12];
    if (lane == 0) { s0[wv] = L0; s1[wv] = L1; }
    __syncthreads();
    if (threadIdx.x == 0) {
        float a = 0.0f, c = 0.0f;
        #pragma unroll
        for (int i = 0; i < 12; ++i) { a += s0[i]; c += s1[i]; }
        ws[blk * 2 + 0] = a;
        ws[blk * 2 + 1] = c;
    }
}

// One block, 256 threads: reduce NSLOT x 2 partials into L[so][st][b],
// then permutation-min. Kernel-boundary dependency makes partials coherent.
__global__ __launch_bounds__(256) void pit_final_kernel(
    const float* __restrict__ ws, float* __restrict__ out, int num_utts)
{
    float acc[16];                       // [so][st][b] = (so*2+st)*4+b
    #pragma unroll
    for (int i = 0; i < 16; ++i) acc[i] = 0.0f;

    for (int slot = threadIdx.x; slot < NSLOT; slot += 256) {
        const int sb = slot / F_FREQ;    // producer's sb
        const int so = sb >> 2;
        const int b  = sb & 3;
        acc[((so * 2 + 0) << 2) + b] += ws[slot * 2 + 0];
        acc[((so * 2 + 1) << 2) + b] += ws[slot * 2 + 1];
    }

    __shared__ float red[16][4];
    const int wave = threadIdx.x >> 6;
    const int lane = threadIdx.x & 63;
    #pragma unroll
    for (int i = 0; i < 16; ++i) {
        float v = acc[i];
        #pragma unroll
        for (int off = 32; off > 0; off >>= 1) v += __shfl_down(v, off, 64);
        if (lane == 0) red[i][wave] = v;
    }
    __syncthreads();

    if (threadIdx.x == 0) {
        float L[16];
        #pragma unroll
        for (int i = 0; i < 16; ++i) L[i] = red[i][0] + red[i][1] + red[i][2] + red[i][3];
        float accu = 0.0f;
        for (int b = 0; b < B_BATCH; ++b) {
            // perm (0,1): L[0][0]+L[1][1];  perm (1,0): L[0][1]+L[1][0]
            const float pid = L[(0 * 2 + 0) * 4 + b] + L[(1 * 2 + 1) * 4 + b];
            const float psw = L[(0 * 2 + 1) * 4 + b] + L[(1 * 2 + 0) * 4 + b];
            const float sc0 = 3.0f * pid / (float)S_SPK;
            const float sc1 = 3.0f * psw / (float)S_SPK;
            accu += fminf(sc0, sc1);
        }
        out[0] = accu / (float)num_utts;
    }
}

extern "C" void kernel_launch(void* const* d_in, const int* in_sizes, int n_in,
                              void* d_out, int out_size, void* d_ws, size_t ws_size,
                              hipStream_t stream) {
    const float* masks = (const float*)d_in[0];
    const float* mixr  = (const float*)d_in[1];
    const float* mixi  = (const float*)d_in[2];
    const float* tgtr  = (const float*)d_in[3];
    const float* tgti  = (const float*)d_in[4];
    // input_sizes values are never used by the reference; only its length is.
    const int num_utts = in_sizes[5];

    float* ws  = (float*)d_ws;
    float* out = (float*)d_out;

    pit_main_kernel<<<NBLK, 768, 0, stream>>>(masks, mixr, mixi, tgtr, tgti, ws);

    pit_final_kernel<<<1, 256, 0, stream>>>(ws, out, num_utts);
}